// Round 13
// baseline (3165.327 us; speedup 1.0000x reference)
//
#include <hip/hip_runtime.h>
#include <hip/hip_bf16.h>

#define Bb 32
#define Ss 1024
#define Vv 32000
#define Ee 512
#define Hh 512
#define Ww 128
#define GXC 3072              // 2 dirs * 3H gate columns
#define MR  (Bb * Ss)         // 32768 GEMM rows

typedef short short8  __attribute__((ext_vector_type(8)));
typedef float floatx4 __attribute__((ext_vector_type(4)));
typedef _Float16 f16x8 __attribute__((ext_vector_type(8)));
typedef unsigned long long u64;

__device__ inline unsigned short bf16bits(float x) {
  return __builtin_bit_cast(unsigned short, __float2bfloat16(x));
}
__device__ inline unsigned f16w(float x) {
  return (unsigned)__builtin_bit_cast(unsigned short, (_Float16)x);
}

template<typename T> __device__ inline T gxstore(float v);
template<> __device__ inline float gxstore<float>(float v) { return v; }
template<> __device__ inline __hip_bfloat16 gxstore<__hip_bfloat16>(float v) { return __float2bfloat16(v); }
template<typename T> __device__ inline float gxload(T v);
template<> __device__ inline float gxload<float>(float v) { return v; }
template<> __device__ inline float gxload<__hip_bfloat16>(__hip_bfloat16 v) { return __bfloat162float(v); }

// ---------------- prep kernels ----------------

__global__ void prep_emb(const float* __restrict__ emb, unsigned short* __restrict__ out) {
  int i = (blockIdx.x * 256 + threadIdx.x) * 4;
  float4 v = *reinterpret_cast<const float4*>(emb + i);
  bool z = (i < Ee);                               // first row = token 0 (padding_idx)
  ushort4 o;
  o.x = z ? (unsigned short)0 : bf16bits(v.x);
  o.y = z ? (unsigned short)0 : bf16bits(v.y);
  o.z = z ? (unsigned short)0 : bf16bits(v.z);
  o.w = z ? (unsigned short)0 : bf16bits(v.w);
  *reinterpret_cast<ushort4*>(out + i) = o;
}

__global__ void prep_wih(const float* __restrict__ wf, const float* __restrict__ wb,
                         unsigned short* __restrict__ out) {
  int i = (blockIdx.x * 256 + threadIdx.x) * 4;   // over 3072*512
  const float* src = (i < 1536 * 512) ? (wf + i) : (wb + (i - 1536 * 512));
  float4 v = *reinterpret_cast<const float4*>(src);
  ushort4 o;
  o.x = bf16bits(v.x); o.y = bf16bits(v.y); o.z = bf16bits(v.z); o.w = bf16bits(v.w);
  *reinterpret_cast<ushort4*>(out + i) = o;
}

// W_hh -> f16 MFMA B-fragments (16x16x32).
// Consumer: block (dir,j), wave w, pair slot s (pair = w*3+s; g=pair>>3, n=pair&7),
// kstep kt, lane l:  uint4 at u4[((dir*4+j)*8 + w)*3072 + (s*16+kt)*64 + l]
//   dword d = pack(W[row][k], W[row][k+1]),
//   row = g*512 + j*128 + n*16 + (l&15),  k = kt*32 + ((l>>4)<<3) + 2d
__global__ void prep_whh(const float* __restrict__ wf, const float* __restrict__ wb,
                         unsigned* __restrict__ out) {
  int o = blockIdx.x * 256 + threadIdx.x;  // < 786432 dwords
  int d    = o & 3;
  int u4   = o >> 2;
  int l    = u4 & 63;
  int kt   = (u4 >> 6) & 15;
  int rest = u4 >> 10;                     // ((dir*4+j)*8 + w)*3 + s, < 192
  int s    = rest % 3;
  int wj   = rest / 3;                     // (dir*4+j)*8 + w
  int w    = wj & 7;
  int dj   = wj >> 3;                      // dir*4 + j
  int j    = dj & 3;
  int dir  = dj >> 2;
  int pair = w * 3 + s;
  int g    = pair >> 3;
  int n    = pair & 7;
  int row  = g * 512 + j * 128 + n * 16 + (l & 15);
  int k    = kt * 32 + ((l >> 4) << 3) + 2 * d;
  const float* W = dir ? wb : wf;
  out[o] = f16w(W[(size_t)row * Hh + k]) | (f16w(W[(size_t)row * Hh + k + 1]) << 16);
}

__global__ void zero_hx(unsigned* __restrict__ hxw) {
  hxw[blockIdx.x * 256 + threadIdx.x] = 0u;   // <<<256,256>>> : 65536 words
}

// ---------------- input-gate GEMM ----------------
template<typename GXT>
__global__ __launch_bounds__(256)
void gx_gemm(const int* __restrict__ seq, const unsigned short* __restrict__ embb,
             const unsigned short* __restrict__ wihb, GXT* __restrict__ gx) {
  __shared__ short As[128][80];
  __shared__ short Bs[128][80];
  __shared__ int toks[128];
  const int tid = threadIdx.x;
  const int m0 = blockIdx.y * 128;
  const int n0 = blockIdx.x * 128;
  if (tid < 128) {
    int r = m0 + tid;                       // row = s*32 + b
    toks[tid] = seq[(r & 31) * Ss + (r >> 5)];
  }
  __syncthreads();
  const int lane = tid & 63, wave = tid >> 6;
  const int wm = (wave >> 1) * 64, wn = (wave & 1) * 64;
  floatx4 zero = {0.f, 0.f, 0.f, 0.f};
  floatx4 acc[4][4];
  #pragma unroll
  for (int a = 0; a < 4; ++a)
    #pragma unroll
    for (int c = 0; c < 4; ++c) acc[a][c] = zero;

  for (int k0 = 0; k0 < Ee; k0 += 64) {
    #pragma unroll
    for (int i = 0; i < 4; ++i) {
      int slot = i * 256 + tid;
      int row = slot >> 3, cq = (slot & 7) * 8;
      uint4 va = *reinterpret_cast<const uint4*>(embb + (size_t)toks[row] * Ee + k0 + cq);
      *reinterpret_cast<uint4*>(&As[row][cq]) = va;
      uint4 vb = *reinterpret_cast<const uint4*>(wihb + (size_t)(n0 + row) * Ee + k0 + cq);
      *reinterpret_cast<uint4*>(&Bs[row][cq]) = vb;
    }
    __syncthreads();
    #pragma unroll
    for (int ks = 0; ks < 2; ++ks) {
      short8 af[4], bfr[4];
      #pragma unroll
      for (int mi = 0; mi < 4; ++mi)
        af[mi] = *reinterpret_cast<const short8*>(&As[wm + mi * 16 + (lane & 15)][ks * 32 + (lane >> 4) * 8]);
      #pragma unroll
      for (int ni = 0; ni < 4; ++ni)
        bfr[ni] = *reinterpret_cast<const short8*>(&Bs[wn + ni * 16 + (lane & 15)][ks * 32 + (lane >> 4) * 8]);
      #pragma unroll
      for (int mi = 0; mi < 4; ++mi)
        #pragma unroll
        for (int ni = 0; ni < 4; ++ni)
          acc[mi][ni] = __builtin_amdgcn_mfma_f32_16x16x32_bf16(af[mi], bfr[ni], acc[mi][ni], 0, 0, 0);
    }
    __syncthreads();
  }
  #pragma unroll
  for (int mi = 0; mi < 4; ++mi) {
    #pragma unroll
    for (int ni = 0; ni < 4; ++ni) {
      int r0 = m0 + wm + mi * 16 + ((lane >> 4) * 4);
      int c  = n0 + wn + ni * 16 + (lane & 15);
      #pragma unroll
      for (int j = 0; j < 4; ++j)
        gx[(size_t)(r0 + j) * GXC + c] = gxstore<GXT>(acc[mi][ni][j]);
    }
  }
}

// ---------------- recurrence: 4 CUs/chain, MFMA core, tagged exchange -------
// Topology + exchange = R11 (proven best: rnn 2.30 ms rocprof). Compute core:
// MFMA reads AGPRs natively -> B-fragments pinned to AGPRs cost zero per-step
// moves (vs R11's dot2 core where AGPR residency implied ~192 accvgpr_reads
// per step, the VALU inflation seen in counters). Pin is PER-32-BIT-COMPONENT
// "+a" (R12 compile lesson: 128-bit tied AGPR tuples are unsupported).
// 8 waves x 3 (gate,ntile) pairs x 16 ksteps of mfma_f32_16x16x32_f16;
// A-operand = h broadcast from LDS (all 16 C-rows equal -> lane L holds the
// result for col = L&15). Gate routing via LDS sbuf[3][128].

#define H16(M) M(0) M(1) M(2) M(3) M(4) M(5) M(6) M(7) \
               M(8) M(9) M(10) M(11) M(12) M(13) M(14) M(15)

#define WDECL(i) uint4 W0_##i, W1_##i, W2_##i;
#define WLOAD(i) W0_##i = wq[(i) * 64]; \
                 W1_##i = wq[(16 + (i)) * 64]; \
                 W2_##i = wq[(32 + (i)) * 64];
#define WPINA(i) asm volatile("" : "+a"(W0_##i.x), "+a"(W0_##i.y), "+a"(W0_##i.z), "+a"(W0_##i.w), \
                                   "+a"(W1_##i.x), "+a"(W1_##i.y), "+a"(W1_##i.z), "+a"(W1_##i.w), \
                                   "+a"(W2_##i.x), "+a"(W2_##i.y), "+a"(W2_##i.z), "+a"(W2_##i.w));
#define CHUNKM(i) { \
  short8 ar = *reinterpret_cast<const short8*>(hbytes + pb + ((i) << 6) + aoff); \
  acc0 = __builtin_amdgcn_mfma_f32_16x16x32_f16(__builtin_bit_cast(f16x8, ar), \
         __builtin_bit_cast(f16x8, W0_##i), acc0, 0, 0, 0); \
  acc1 = __builtin_amdgcn_mfma_f32_16x16x32_f16(__builtin_bit_cast(f16x8, ar), \
         __builtin_bit_cast(f16x8, W1_##i), acc1, 0, 0, 0); \
  acc2 = __builtin_amdgcn_mfma_f32_16x16x32_f16(__builtin_bit_cast(f16x8, ar), \
         __builtin_bit_cast(f16x8, W2_##i), acc2, 0, 0, 0); }

#define TAGOK1(a, want) \
  (((((unsigned)((a) >> 16)) & 0xffffu) == (want)) & \
   ((((unsigned)((a) >> 48))) == (want)))

template<typename GXT>
__global__ __launch_bounds__(512, 2)
void rnn_kernel(const GXT* __restrict__ gx, const unsigned* __restrict__ whh2,
                const float* __restrict__ bih_f, const float* __restrict__ bhh_f,
                const float* __restrict__ bih_b, const float* __restrict__ bhh_b,
                const int* __restrict__ layout, float* __restrict__ out,
                unsigned* __restrict__ hx) {
  __shared__ unsigned hbufw[512];            // h f16: 2 parities x 512 cols
  __shared__ float sbuf[3][128];             // gate pre-activation routing
  __shared__ int lay[Ww + 1];
  const int tid   = threadIdx.x;
  const int w     = tid >> 6;
  const int lane  = tid & 63;
  const int j     = blockIdx.x >> 6;         // shard
  const int chain = blockIdx.x & 63;
  const int dir   = chain >> 5;
  const int b     = chain & 31;

  const uint4* wq = reinterpret_cast<const uint4*>(whh2)
                    + (size_t)((dir * 4 + j) * 8 + w) * 3072 + lane;
  H16(WDECL)
  H16(WLOAD)
  H16(WPINA)

  float br0 = 0.f, bz0 = 0.f, bi2 = 0.f, bh2 = 0.f;
  if (tid < 128) {
    const float* bi = dir ? bih_b : bih_f;
    const float* bv = dir ? bhh_b : bhh_f;
    int col = j * 128 + tid;
    br0 = bi[col] + bv[col];
    bz0 = bi[512 + col] + bv[512 + col];
    bi2 = bi[1024 + col];
    bh2 = bv[1024 + col];
  }
  if (tid <= Ww) lay[tid] = layout[b * (Ww + 1) + tid];
  hbufw[tid] = 0u;                           // h0 = 0, both parities (512 dwords)
  __syncthreads();

  float h = 0.f, mx = -3.0e38f;
  int t = dir ? (Ss - 1) : 0;
  const int tstep = dir ? -1 : 1;
  int seg = dir ? (Ww - 1) : 0;
  int p = 0;
  const char* hbytes = reinterpret_cast<const char*>(hbufw);
  const int aoff = (lane >> 4) << 4;

  float gr = 0.f, gz = 0.f, gn = 0.f;        // gx prefetch (current step)
  if (tid < 128) {
    const GXT* gp = gx + (size_t)(t * Bb + b) * GXC + dir * 1536 + j * 128 + tid;
    gr = gxload<GXT>(gp[0]); gz = gxload<GXT>(gp[512]); gn = gxload<GXT>(gp[1024]);
  }

  #pragma unroll 1
  for (int it = 0; it < Ss; ++it, t += tstep) {
    float ngr = 0.f, ngz = 0.f, ngn = 0.f;
    if (tid < 128 && it + 1 < Ss) {          // issue NEXT step's gx now
      const GXT* gp = gx + (size_t)((t + tstep) * Bb + b) * GXC + dir * 1536 + j * 128 + tid;
      ngr = gxload<GXT>(gp[0]); ngz = gxload<GXT>(gp[512]); ngn = gxload<GXT>(gp[1024]);
    }
    // ---- MFMA phase: gh[384 cols] for this shard ----
    floatx4 acc0 = {0.f, 0.f, 0.f, 0.f};
    floatx4 acc1 = acc0, acc2 = acc0;
    const int pb = p << 10;                  // parity byte base
    H16(CHUNKM)
    H16(WPINA)                               // in-loop: keeps frags AGPR-resident
    if (lane < 16) {                         // all C-rows equal; row 0 suffices
      int p0 = w * 3;
      sbuf[p0 >> 3][((p0 & 7) << 4) + lane]             = acc0[0];
      sbuf[(p0 + 1) >> 3][(((p0 + 1) & 7) << 4) + lane] = acc1[0];
      sbuf[(p0 + 2) >> 3][(((p0 + 2) & 7) << 4) + lane] = acc2[0];
    }
    __syncthreads();                         // barrier 1: sbuf ready
    const int P = p ^ 1;
    if (tid < 128) {                         // epilogue: one col per thread
      float rs = gr + br0 + sbuf[0][tid];
      float zs = gz + bz0 + sbuf[1][tid];
      float nh = bh2 + sbuf[2][tid];         // gh_n incl. b_hh_n (scaled by r)
      float r = 1.f / (1.f + __expf(-rs));
      float z = 1.f / (1.f + __expf(-zs));
      float x = gn + bi2 + r * nh;
      x = fminf(fmaxf(x, -15.f), 15.f);
      float e = __expf(2.f * x);
      float n = (e - 1.f) / (e + 1.f);       // tanh
      h = (1.f - z) * n + z * h;
      unsigned hb16 = (unsigned)__builtin_bit_cast(unsigned short, (_Float16)h);
      __hip_atomic_store(hx + ((((size_t)P * 64 + chain) * 4 + j) << 7) + tid,
                         (((unsigned)(it + 1)) << 16) | hb16,
                         __ATOMIC_RELAXED, __HIP_MEMORY_SCOPE_AGENT);
      mx = fmaxf(mx, h);
      reinterpret_cast<_Float16*>(hbufw)[P * 512 + j * 128 + tid] = (_Float16)h;
      bool flush = dir ? (t == lay[seg]) : (t + 1 == lay[seg + 1]);
      if (flush) {
        out[(size_t)(b * Ww + seg) * 1024 + dir * 512 + j * 128 + tid] = mx;
        mx = -3.0e38f;
        seg += tstep;
      }
    }
    // ---- gather (R11 verbatim): 192 threads x one u64, parity P ----
    if (it + 1 < Ss && tid < 192) {
      int s2 = tid >> 6, qd = tid & 63;
      int sib = s2 + (s2 >= j);
      const u64* src = reinterpret_cast<const u64*>(
          hx + ((((size_t)P * 64 + chain) * 4 + sib) << 7) + (qd << 1));
      const unsigned want = (unsigned)(it + 1);
      u64 a;
      for (;;) {
        a = __hip_atomic_load(src, __ATOMIC_RELAXED, __HIP_MEMORY_SCOPE_AGENT);
        if (TAGOK1(a, want)) break;
      }
      hbufw[P * 256 + sib * 64 + qd] =
          ((unsigned)a & 0xffffu) | (((unsigned)(a >> 32) & 0xffffu) << 16);
    }
    __syncthreads();                         // barrier 2: parity P complete
    p = P;
    gr = ngr; gz = ngz; gn = ngn;
  }
  if (tid < 128)                             // final hidden [2][B][H]
    out[(size_t)Bb * Ww * 1024 + (size_t)dir * (Bb * Hh) + (size_t)b * Hh + j * 128 + tid] = h;
}

// ---------------- host launcher ----------------
extern "C" void kernel_launch(void* const* d_in, const int* in_sizes, int n_in,
                              void* d_out, int out_size, void* d_ws, size_t ws_size,
                              hipStream_t stream) {
  const int*   seq    = (const int*)  d_in[0];
  const int*   layout = (const int*)  d_in[3];
  const float* emb    = (const float*)d_in[4];
  const float* Wih_f  = (const float*)d_in[5];
  const float* Whh_f  = (const float*)d_in[6];
  const float* bih_f  = (const float*)d_in[7];
  const float* bhh_f  = (const float*)d_in[8];
  const float* Wih_b  = (const float*)d_in[9];
  const float* Whh_b  = (const float*)d_in[10];
  const float* bih_b  = (const float*)d_in[11];
  const float* bhh_b  = (const float*)d_in[12];
  float* out = (float*)d_out;

  char* ws = (char*)d_ws;
  unsigned short* embb  = (unsigned short*)ws;                      // 32,768,000 B
  unsigned short* wihb  = (unsigned short*)(ws + 32768000);         //  3,145,728 B
  unsigned*       whh2  = (unsigned*)      (ws + 35913728);         //  3,145,728 B
  unsigned*       hxw   = (unsigned*)      (ws + 39059456);         //    262,144 B
  void*           gxp   = (void*)          (ws + 39321600);

  const size_t need_f32 = 39321600ULL + (size_t)MR * GXC * 4;       // ~442.0 MB
  const size_t need_b16 = 39321600ULL + (size_t)MR * GXC * 2;       // ~240.6 MB
  if (ws_size < need_b16) return;

  prep_emb<<<(Vv * Ee) / 4 / 256, 256, 0, stream>>>(emb, embb);
  prep_wih<<<(GXC * Ee) / 4 / 256, 256, 0, stream>>>(Wih_f, Wih_b, wihb);
  prep_whh<<<786432 / 256, 256, 0, stream>>>(Whh_f, Whh_b, whh2);
  zero_hx<<<256, 256, 0, stream>>>(hxw);      // stream-ordered: runs before rnn

  if (ws_size >= need_f32) {
    gx_gemm<float><<<dim3(GXC / 128, MR / 128), 256, 0, stream>>>(seq, embb, wihb, (float*)gxp);
    rnn_kernel<float><<<256, 512, 0, stream>>>((const float*)gxp, whh2,
                                               bih_f, bhh_f, bih_b, bhh_b, layout, out, hxw);
  } else {
    gx_gemm<__hip_bfloat16><<<dim3(GXC / 128, MR / 128), 256, 0, stream>>>(seq, embb, wihb, (__hip_bfloat16*)gxp);
    rnn_kernel<__hip_bfloat16><<<256, 512, 0, stream>>>((const __hip_bfloat16*)gxp, whh2,
                                                        bih_f, bhh_f, bih_b, bhh_b, layout, out, hxw);
  }
}

// Round 14
// 2692.684 us; speedup vs baseline: 1.1755x; 1.1755x over previous
//
#include <hip/hip_runtime.h>
#include <hip/hip_bf16.h>

#define Bb 32
#define Ss 1024
#define Vv 32000
#define Ee 512
#define Hh 512
#define Ww 128
#define GXC 3072              // 2 dirs * 3H gate columns
#define MR  (Bb * Ss)         // 32768 GEMM rows

typedef short short8  __attribute__((ext_vector_type(8)));
typedef float floatx4 __attribute__((ext_vector_type(4)));
typedef _Float16 f16x2 __attribute__((ext_vector_type(2)));
typedef unsigned long long u64;

__device__ inline float dot2f(unsigned w, unsigned h, float acc) {
  return __builtin_amdgcn_fdot2(__builtin_bit_cast(f16x2, w),
                                __builtin_bit_cast(f16x2, h), acc, false);
}
__device__ inline unsigned short bf16bits(float x) {
  return __builtin_bit_cast(unsigned short, __float2bfloat16(x));
}

template<typename T> __device__ inline T gxstore(float v);
template<> __device__ inline float gxstore<float>(float v) { return v; }
template<> __device__ inline __hip_bfloat16 gxstore<__hip_bfloat16>(float v) { return __float2bfloat16(v); }
template<typename T> __device__ inline float gxload(T v);
template<> __device__ inline float gxload<float>(float v) { return v; }
template<> __device__ inline float gxload<__hip_bfloat16>(__hip_bfloat16 v) { return __bfloat162float(v); }

// ---------------- prep kernels ----------------

__global__ void prep_emb(const float* __restrict__ emb, unsigned short* __restrict__ out) {
  int i = (blockIdx.x * 256 + threadIdx.x) * 4;
  float4 v = *reinterpret_cast<const float4*>(emb + i);
  bool z = (i < Ee);                               // first row = token 0 (padding_idx)
  ushort4 o;
  o.x = z ? (unsigned short)0 : bf16bits(v.x);
  o.y = z ? (unsigned short)0 : bf16bits(v.y);
  o.z = z ? (unsigned short)0 : bf16bits(v.z);
  o.w = z ? (unsigned short)0 : bf16bits(v.w);
  *reinterpret_cast<ushort4*>(out + i) = o;
}

__global__ void prep_wih(const float* __restrict__ wf, const float* __restrict__ wb,
                         unsigned short* __restrict__ out) {
  int i = (blockIdx.x * 256 + threadIdx.x) * 4;   // over 3072*512
  const float* src = (i < 1536 * 512) ? (wf + i) : (wb + (i - 1536 * 512));
  float4 v = *reinterpret_cast<const float4*>(src);
  ushort4 o;
  o.x = bf16bits(v.x); o.y = bf16bits(v.y); o.z = bf16bits(v.z); o.w = bf16bits(v.w);
  *reinterpret_cast<ushort4*>(out + i) = o;
}

// W_hh -> f16x2 for the 4-shard rnn (512 thr/block):
//   uint4 chunk: out_u4[ ((dir*4 + j)*48 + g*16 + i)*512 + tid ]
//   word m = pack(W[row][2kp], W[row][2kp+1])
//   tid: c=tid>>2 (local hcol), q=tid&3 (K-quarter)
//   row = g*512 + j*128 + c,  kp = q*64 + i*4 + m
__global__ void prep_whh(const float* __restrict__ wf, const float* __restrict__ wb,
                         unsigned* __restrict__ out) {
  int o = blockIdx.x * 256 + threadIdx.x;  // < 786432 words
  int m    = o & 3;
  int u4   = o >> 2;
  int tid  = u4 & 511;
  int rest = u4 >> 9;
  int i    = rest & 15;
  int rest2 = rest >> 4;                   // (dir*4+j)*3 + g, < 24
  int g    = rest2 % 3;
  int rest3 = rest2 / 3;                   // dir*4 + j
  int j    = rest3 & 3;
  int dir  = rest3 >> 2;
  int c    = tid >> 2;
  int q    = tid & 3;
  int row  = g * 512 + j * 128 + c;
  int kp   = q * 64 + i * 4 + m;
  const float* W = dir ? wb : wf;
  unsigned lo = __builtin_bit_cast(unsigned short, (_Float16)W[(size_t)row * Hh + 2 * kp]);
  unsigned hi = __builtin_bit_cast(unsigned short, (_Float16)W[(size_t)row * Hh + 2 * kp + 1]);
  out[o] = lo | (hi << 16);
}

__global__ void zero_hx(unsigned* __restrict__ hxw) {
  hxw[blockIdx.x * 256 + threadIdx.x] = 0u;   // <<<256,256>>> : 65536 words
}

// ---------------- input-gate GEMM ----------------
template<typename GXT>
__global__ __launch_bounds__(256)
void gx_gemm(const int* __restrict__ seq, const unsigned short* __restrict__ embb,
             const unsigned short* __restrict__ wihb, GXT* __restrict__ gx) {
  __shared__ short As[128][80];
  __shared__ short Bs[128][80];
  __shared__ int toks[128];
  const int tid = threadIdx.x;
  const int m0 = blockIdx.y * 128;
  const int n0 = blockIdx.x * 128;
  if (tid < 128) {
    int r = m0 + tid;                       // row = s*32 + b
    toks[tid] = seq[(r & 31) * Ss + (r >> 5)];
  }
  __syncthreads();
  const int lane = tid & 63, wave = tid >> 6;
  const int wm = (wave >> 1) * 64, wn = (wave & 1) * 64;
  floatx4 zero = {0.f, 0.f, 0.f, 0.f};
  floatx4 acc[4][4];
  #pragma unroll
  for (int a = 0; a < 4; ++a)
    #pragma unroll
    for (int c = 0; c < 4; ++c) acc[a][c] = zero;

  for (int k0 = 0; k0 < Ee; k0 += 64) {
    #pragma unroll
    for (int i = 0; i < 4; ++i) {
      int slot = i * 256 + tid;
      int row = slot >> 3, cq = (slot & 7) * 8;
      uint4 va = *reinterpret_cast<const uint4*>(embb + (size_t)toks[row] * Ee + k0 + cq);
      *reinterpret_cast<uint4*>(&As[row][cq]) = va;
      uint4 vb = *reinterpret_cast<const uint4*>(wihb + (size_t)(n0 + row) * Ee + k0 + cq);
      *reinterpret_cast<uint4*>(&Bs[row][cq]) = vb;
    }
    __syncthreads();
    #pragma unroll
    for (int ks = 0; ks < 2; ++ks) {
      short8 af[4], bfr[4];
      #pragma unroll
      for (int mi = 0; mi < 4; ++mi)
        af[mi] = *reinterpret_cast<const short8*>(&As[wm + mi * 16 + (lane & 15)][ks * 32 + (lane >> 4) * 8]);
      #pragma unroll
      for (int ni = 0; ni < 4; ++ni)
        bfr[ni] = *reinterpret_cast<const short8*>(&Bs[wn + ni * 16 + (lane & 15)][ks * 32 + (lane >> 4) * 8]);
      #pragma unroll
      for (int mi = 0; mi < 4; ++mi)
        #pragma unroll
        for (int ni = 0; ni < 4; ++ni)
          acc[mi][ni] = __builtin_amdgcn_mfma_f32_16x16x32_bf16(af[mi], bfr[ni], acc[mi][ni], 0, 0, 0);
    }
    __syncthreads();
  }
  #pragma unroll
  for (int mi = 0; mi < 4; ++mi) {
    #pragma unroll
    for (int ni = 0; ni < 4; ++ni) {
      int r0 = m0 + wm + mi * 16 + ((lane >> 4) * 4);
      int c  = n0 + wn + ni * 16 + (lane & 15);
      #pragma unroll
      for (int j = 0; j < 4; ++j)
        gx[(size_t)(r0 + j) * GXC + c] = gxstore<GXT>(acc[mi][ni][j]);
    }
  }
}

// ---------------- recurrence: 4 CUs/chain, fence-free tagged exchange -------
// R11 structure (best: rnn 2.30 ms rocprof) + two MALL-traffic cuts, after
// R10/R13 showed the step is exchange-latency/contention-bound:
//  (1) packed u64 publish: adjacent cols paired via intra-wave __shfl_down(4)
//      (both lanes active in the q==0 branch) -> 64 stores/block/step instead
//      of 128, and each gathered u64 becomes visible atomically (no
//      half-updated-pair re-polls).
//  (2) s_sleep(1) poll throttle: failed check sleeps 64 cyc before reissuing,
//      cutting chip-wide spin traffic ~2-3x at ~27ns detection cost.
// Protocol otherwise unchanged: tagged word {tag16=it+1 | h_f16}, relaxed
// agent atomics, 2-parity buffer, no fences, no placement assumptions.

#define H16(M) M(0) M(1) M(2) M(3) M(4) M(5) M(6) M(7) \
               M(8) M(9) M(10) M(11) M(12) M(13) M(14) M(15)

#define WDECL(i) uint4 W0_##i, W1_##i, W2_##i;
#define WLOAD(i) W0_##i = wq[(i) * 512]; \
                 W1_##i = wq[(16 + (i)) * 512]; \
                 W2_##i = wq[(32 + (i)) * 512];
#define WPIN(i) asm volatile("" : "+v"(W0_##i.x), "+v"(W0_##i.y), "+v"(W0_##i.z), "+v"(W0_##i.w), \
                                  "+v"(W1_##i.x), "+v"(W1_##i.y), "+v"(W1_##i.z), "+v"(W1_##i.w), \
                                  "+v"(W2_##i.x), "+v"(W2_##i.y), "+v"(W2_##i.z), "+v"(W2_##i.w));
#define CHUNK(i) { uint4 Hq = hq4[i]; \
  s0 = dot2f(W0_##i.x, Hq.x, s0); s0 = dot2f(W0_##i.y, Hq.y, s0); \
  s0 = dot2f(W0_##i.z, Hq.z, s0); s0 = dot2f(W0_##i.w, Hq.w, s0); \
  s1 = dot2f(W1_##i.x, Hq.x, s1); s1 = dot2f(W1_##i.y, Hq.y, s1); \
  s1 = dot2f(W1_##i.z, Hq.z, s1); s1 = dot2f(W1_##i.w, Hq.w, s1); \
  s2 = dot2f(W2_##i.x, Hq.x, s2); s2 = dot2f(W2_##i.y, Hq.y, s2); \
  s2 = dot2f(W2_##i.z, Hq.z, s2); s2 = dot2f(W2_##i.w, Hq.w, s2); }

#define TAGOK1(a, want) \
  (((((unsigned)((a) >> 16)) & 0xffffu) == (want)) & \
   ((((unsigned)((a) >> 48))) == (want)))

template<typename GXT>
__global__ __launch_bounds__(512, 2)
void rnn_kernel(const GXT* __restrict__ gx, const unsigned* __restrict__ whh2,
                const float* __restrict__ bih_f, const float* __restrict__ bhh_f,
                const float* __restrict__ bih_b, const float* __restrict__ bhh_b,
                const int* __restrict__ layout, float* __restrict__ out,
                unsigned* __restrict__ hx) {
  __shared__ unsigned hbufw[544];            // 2 parities x (4 quarters x 68 words)
  __shared__ int lay[Ww + 1];
  const int tid   = threadIdx.x;
  const int j     = blockIdx.x >> 6;         // shard: siblings {c, c+64, c+128, c+192}
  const int chain = blockIdx.x & 63;
  const int dir   = chain >> 5;
  const int b     = chain & 31;
  const int c     = tid >> 2;                // local hcol 0..127
  const int q     = tid & 3;                 // K-quarter
  const int col   = j * 128 + c;             // global hcol

  const uint4* wq = reinterpret_cast<const uint4*>(whh2)
                    + (size_t)(dir * 4 + j) * 48 * 512 + tid;
  H16(WDECL)
  H16(WLOAD)
  H16(WPIN)

  float bi0 = 0.f, bi1 = 0.f, bi2 = 0.f, bh0 = 0.f, bh1 = 0.f, bh2 = 0.f;
  if (q == 0) {
    const float* bi = dir ? bih_b : bih_f;
    const float* bh = dir ? bhh_b : bhh_f;
    bi0 = bi[col]; bi1 = bi[512 + col]; bi2 = bi[1024 + col];
    bh0 = bh[col]; bh1 = bh[512 + col]; bh2 = bh[1024 + col];
  }
  if (tid <= Ww) lay[tid] = layout[b * (Ww + 1) + tid];
  hbufw[tid] = 0u;
  if (tid < 32) hbufw[512 + tid] = 0u;       // h0 = 0, both parities
  __syncthreads();

  float h = 0.f, mx = -3.0e38f;
  int t = dir ? (Ss - 1) : 0;
  const int tstep = dir ? -1 : 1;
  int seg = dir ? (Ww - 1) : 0;
  int p = 0;

  // gx prefetch: current step's values live in (gr,gz,gn)
  float gr = 0.f, gz = 0.f, gn = 0.f;
  if (q == 0) {
    const GXT* gp = gx + (size_t)(t * Bb + b) * GXC + dir * 1536 + col;
    gr = gxload<GXT>(gp[0]); gz = gxload<GXT>(gp[512]); gn = gxload<GXT>(gp[1024]);
  }

  #pragma unroll 1
  for (int it = 0; it < Ss; ++it, t += tstep) {
    float ngr = 0.f, ngz = 0.f, ngn = 0.f;
    if (q == 0 && it + 1 < Ss) {             // issue NEXT step's gx now (~2us cover)
      const GXT* gp = gx + (size_t)((t + tstep) * Bb + b) * GXC + dir * 1536 + col;
      ngr = gxload<GXT>(gp[0]); ngz = gxload<GXT>(gp[512]); ngn = gxload<GXT>(gp[1024]);
    }
    float s0 = 0.f, s1 = 0.f, s2 = 0.f;
    const uint4* hq4 = reinterpret_cast<const uint4*>(hbufw) + p * 68 + q * 17;
    H16(CHUNK)
    H16(WPIN)                                // keep weights loop-carried in regs
    { float u;                               // quad butterfly over K-quarters
      u = __shfl_xor(s0, 1); s0 += u; u = __shfl_xor(s0, 2); s0 += u;
      u = __shfl_xor(s1, 1); s1 += u; u = __shfl_xor(s1, 2); s1 += u;
      u = __shfl_xor(s2, 1); s2 += u; u = __shfl_xor(s2, 2); s2 += u; }
    const int P = p ^ 1;
    if (q == 0) {
      float rs = gr + bi0 + bh0 + s0;
      float zs = gz + bi1 + bh1 + s1;
      float nh = bh2 + s2;                   // gh_n incl. b_hh_n (scaled by r)
      float r = 1.f / (1.f + __expf(-rs));
      float z = 1.f / (1.f + __expf(-zs));
      float x = gn + bi2 + r * nh;
      x = fminf(fmaxf(x, -15.f), 15.f);
      float e = __expf(2.f * x);
      float n = (e - 1.f) / (e + 1.f);       // tanh
      h = (1.f - z) * n + z * h;
      unsigned hb16 = (unsigned)__builtin_bit_cast(unsigned short, (_Float16)h);
      unsigned pv = (((unsigned)(it + 1)) << 16) | hb16;
      // packed u64 publish: pair (c even, c+1) via shfl_down(4); both lanes
      // are q==0 (lane%4==0) and active here; pairs stay within a wave.
      unsigned pv_hi = __shfl_down(pv, 4);
      if ((c & 1) == 0) {
        u64 packed = (u64)pv | ((u64)pv_hi << 32);
        __hip_atomic_store(reinterpret_cast<u64*>(
            hx + ((((size_t)P * 64 + chain) * 4 + j) << 7) + c), packed,
            __ATOMIC_RELAXED, __HIP_MEMORY_SCOPE_AGENT);
      }
      mx = fmaxf(mx, h);
      reinterpret_cast<_Float16*>(hbufw)[((P * 272 + j * 68 + (c >> 1)) << 1) | (c & 1)]
          = (_Float16)h;                     // own shard of h_{it+1} (local)
      bool flush = dir ? (t == lay[seg]) : (t + 1 == lay[seg + 1]);
      if (flush) {
        out[(size_t)(b * Ww + seg) * 1024 + dir * 512 + col] = mx;
        mx = -3.0e38f;
        seg += tstep;
      }
    }
    // gather: touches only parity-P sibling slots (disjoint from this step's
    // parity-p reads and own-slot writes); barrier C orders for next step.
    if (it + 1 < Ss && tid < 192) {          // 192 threads x ONE u64 each
      int s = tid >> 6, qd = tid & 63;       // u64 qd covers columns 2qd, 2qd+1
      int sib = s + (s >= j);
      const u64* src = reinterpret_cast<const u64*>(
          hx + ((((size_t)P * 64 + chain) * 4 + sib) << 7) + (qd << 1));
      const unsigned want = (unsigned)(it + 1);
      u64 a;
      for (;;) {
        a = __hip_atomic_load(src, __ATOMIC_RELAXED, __HIP_MEMORY_SCOPE_AGENT);
        if (TAGOK1(a, want)) break;
        __builtin_amdgcn_s_sleep(1);         // throttle spin traffic (64 cyc)
      }
      hbufw[P * 272 + sib * 68 + qd] =
          ((unsigned)a & 0xffffu) | (((unsigned)(a >> 32) & 0xffffu) << 16);
    }
    __syncthreads();                         // C: full h_{it+1} in LDS
    p = P;
    gr = ngr; gz = ngz; gn = ngn;
  }
  if (q == 0)                                // final hidden [2][B][H]
    out[(size_t)Bb * Ww * 1024 + (size_t)dir * (Bb * Hh) + b * Hh + col] = h;
}

// ---------------- host launcher ----------------
extern "C" void kernel_launch(void* const* d_in, const int* in_sizes, int n_in,
                              void* d_out, int out_size, void* d_ws, size_t ws_size,
                              hipStream_t stream) {
  const int*   seq    = (const int*)  d_in[0];
  const int*   layout = (const int*)  d_in[3];
  const float* emb    = (const float*)d_in[4];
  const float* Wih_f  = (const float*)d_in[5];
  const float* Whh_f  = (const float*)d_in[6];
  const float* bih_f  = (const float*)d_in[7];
  const float* bhh_f  = (const float*)d_in[8];
  const float* Wih_b  = (const float*)d_in[9];
  const float* Whh_b  = (const float*)d_in[10];
  const float* bih_b  = (const float*)d_in[11];
  const float* bhh_b  = (const float*)d_in[12];
  float* out = (float*)d_out;

  char* ws = (char*)d_ws;
  unsigned short* embb  = (unsigned short*)ws;                      // 32,768,000 B
  unsigned short* wihb  = (unsigned short*)(ws + 32768000);         //  3,145,728 B
  unsigned*       whh2  = (unsigned*)      (ws + 35913728);         //  3,145,728 B
  unsigned*       hxw   = (unsigned*)      (ws + 39059456);         //    262,144 B
  void*           gxp   = (void*)          (ws + 39321600);

  const size_t need_f32 = 39321600ULL + (size_t)MR * GXC * 4;       // ~442.0 MB
  const size_t need_b16 = 39321600ULL + (size_t)MR * GXC * 2;       // ~240.6 MB
  if (ws_size < need_b16) return;

  prep_emb<<<(Vv * Ee) / 4 / 256, 256, 0, stream>>>(emb, embb);
  prep_wih<<<(GXC * Ee) / 4 / 256, 256, 0, stream>>>(Wih_f, Wih_b, wihb);
  prep_whh<<<(2 * 4 * 48 * 512 * 4) / 256, 256, 0, stream>>>(Whh_f, Whh_b, whh2);
  zero_hx<<<256, 256, 0, stream>>>(hxw);      // stream-ordered: runs before rnn

  if (ws_size >= need_f32) {
    gx_gemm<float><<<dim3(GXC / 128, MR / 128), 256, 0, stream>>>(seq, embb, wihb, (float*)gxp);
    rnn_kernel<float><<<256, 512, 0, stream>>>((const float*)gxp, whh2,
                                               bih_f, bhh_f, bih_b, bhh_b, layout, out, hxw);
  } else {
    gx_gemm<__hip_bfloat16><<<dim3(GXC / 128, MR / 128), 256, 0, stream>>>(seq, embb, wihb, (__hip_bfloat16*)gxp);
    rnn_kernel<__hip_bfloat16><<<256, 512, 0, stream>>>((const __hip_bfloat16*)gxp, whh2,
                                                        bih_f, bhh_f, bih_b, bhh_b, layout, out, hxw);
  }
}

// Round 15
// 2329.574 us; speedup vs baseline: 1.3588x; 1.1559x over previous
//
#include <hip/hip_runtime.h>
#include <hip/hip_bf16.h>

#define Bb 32
#define Ss 1024
#define Vv 32000
#define Ee 512
#define Hh 512
#define Ww 128
#define GXC 3072              // 2 dirs * 3H gate columns
#define MR  (Bb * Ss)         // 32768 GEMM rows

typedef short short8  __attribute__((ext_vector_type(8)));
typedef float floatx4 __attribute__((ext_vector_type(4)));
typedef _Float16 f16x2 __attribute__((ext_vector_type(2)));
typedef unsigned long long u64;

__device__ inline float dot2f(unsigned w, unsigned h, float acc) {
  return __builtin_amdgcn_fdot2(__builtin_bit_cast(f16x2, w),
                                __builtin_bit_cast(f16x2, h), acc, false);
}
__device__ inline unsigned short bf16bits(float x) {
  return __builtin_bit_cast(unsigned short, __float2bfloat16(x));
}

template<typename T> __device__ inline T gxstore(float v);
template<> __device__ inline float gxstore<float>(float v) { return v; }
template<> __device__ inline __hip_bfloat16 gxstore<__hip_bfloat16>(float v) { return __float2bfloat16(v); }
template<typename T> __device__ inline float gxload(T v);
template<> __device__ inline float gxload<float>(float v) { return v; }
template<> __device__ inline float gxload<__hip_bfloat16>(__hip_bfloat16 v) { return __bfloat162float(v); }

// ---------------- prep kernels ----------------

__global__ void prep_emb(const float* __restrict__ emb, unsigned short* __restrict__ out) {
  int i = (blockIdx.x * 256 + threadIdx.x) * 4;
  float4 v = *reinterpret_cast<const float4*>(emb + i);
  bool z = (i < Ee);                               // first row = token 0 (padding_idx)
  ushort4 o;
  o.x = z ? (unsigned short)0 : bf16bits(v.x);
  o.y = z ? (unsigned short)0 : bf16bits(v.y);
  o.z = z ? (unsigned short)0 : bf16bits(v.z);
  o.w = z ? (unsigned short)0 : bf16bits(v.w);
  *reinterpret_cast<ushort4*>(out + i) = o;
}

__global__ void prep_wih(const float* __restrict__ wf, const float* __restrict__ wb,
                         unsigned short* __restrict__ out) {
  int i = (blockIdx.x * 256 + threadIdx.x) * 4;   // over 3072*512
  const float* src = (i < 1536 * 512) ? (wf + i) : (wb + (i - 1536 * 512));
  float4 v = *reinterpret_cast<const float4*>(src);
  ushort4 o;
  o.x = bf16bits(v.x); o.y = bf16bits(v.y); o.z = bf16bits(v.z); o.w = bf16bits(v.w);
  *reinterpret_cast<ushort4*>(out + i) = o;
}

// W_hh -> f16x2 for the 4-shard rnn (512 thr/block):
//   uint4 chunk: out_u4[ ((dir*4 + j)*48 + g*16 + i)*512 + tid ]
//   word m = pack(W[row][2kp], W[row][2kp+1])
//   tid: c=tid>>2 (local hcol), q=tid&3 (K-quarter)
//   row = g*512 + j*128 + c,  kp = q*64 + i*4 + m
__global__ void prep_whh(const float* __restrict__ wf, const float* __restrict__ wb,
                         unsigned* __restrict__ out) {
  int o = blockIdx.x * 256 + threadIdx.x;  // < 786432 words
  int m    = o & 3;
  int u4   = o >> 2;
  int tid  = u4 & 511;
  int rest = u4 >> 9;
  int i    = rest & 15;
  int rest2 = rest >> 4;                   // (dir*4+j)*3 + g, < 24
  int g    = rest2 % 3;
  int rest3 = rest2 / 3;                   // dir*4 + j
  int j    = rest3 & 3;
  int dir  = rest3 >> 2;
  int c    = tid >> 2;
  int q    = tid & 3;
  int row  = g * 512 + j * 128 + c;
  int kp   = q * 64 + i * 4 + m;
  const float* W = dir ? wb : wf;
  unsigned lo = __builtin_bit_cast(unsigned short, (_Float16)W[(size_t)row * Hh + 2 * kp]);
  unsigned hi = __builtin_bit_cast(unsigned short, (_Float16)W[(size_t)row * Hh + 2 * kp + 1]);
  out[o] = lo | (hi << 16);
}

__global__ void zero_hx(unsigned* __restrict__ hxw) {
  hxw[blockIdx.x * 256 + threadIdx.x] = 0u;   // <<<256,256>>> : 65536 words
}

// ---------------- input-gate GEMM ----------------
template<typename GXT>
__global__ __launch_bounds__(256)
void gx_gemm(const int* __restrict__ seq, const unsigned short* __restrict__ embb,
             const unsigned short* __restrict__ wihb, GXT* __restrict__ gx) {
  __shared__ short As[128][80];
  __shared__ short Bs[128][80];
  __shared__ int toks[128];
  const int tid = threadIdx.x;
  const int m0 = blockIdx.y * 128;
  const int n0 = blockIdx.x * 128;
  if (tid < 128) {
    int r = m0 + tid;                       // row = s*32 + b
    toks[tid] = seq[(r & 31) * Ss + (r >> 5)];
  }
  __syncthreads();
  const int lane = tid & 63, wave = tid >> 6;
  const int wm = (wave >> 1) * 64, wn = (wave & 1) * 64;
  floatx4 zero = {0.f, 0.f, 0.f, 0.f};
  floatx4 acc[4][4];
  #pragma unroll
  for (int a = 0; a < 4; ++a)
    #pragma unroll
    for (int c = 0; c < 4; ++c) acc[a][c] = zero;

  for (int k0 = 0; k0 < Ee; k0 += 64) {
    #pragma unroll
    for (int i = 0; i < 4; ++i) {
      int slot = i * 256 + tid;
      int row = slot >> 3, cq = (slot & 7) * 8;
      uint4 va = *reinterpret_cast<const uint4*>(embb + (size_t)toks[row] * Ee + k0 + cq);
      *reinterpret_cast<uint4*>(&As[row][cq]) = va;
      uint4 vb = *reinterpret_cast<const uint4*>(wihb + (size_t)(n0 + row) * Ee + k0 + cq);
      *reinterpret_cast<uint4*>(&Bs[row][cq]) = vb;
    }
    __syncthreads();
    #pragma unroll
    for (int ks = 0; ks < 2; ++ks) {
      short8 af[4], bfr[4];
      #pragma unroll
      for (int mi = 0; mi < 4; ++mi)
        af[mi] = *reinterpret_cast<const short8*>(&As[wm + mi * 16 + (lane & 15)][ks * 32 + (lane >> 4) * 8]);
      #pragma unroll
      for (int ni = 0; ni < 4; ++ni)
        bfr[ni] = *reinterpret_cast<const short8*>(&Bs[wn + ni * 16 + (lane & 15)][ks * 32 + (lane >> 4) * 8]);
      #pragma unroll
      for (int mi = 0; mi < 4; ++mi)
        #pragma unroll
        for (int ni = 0; ni < 4; ++ni)
          acc[mi][ni] = __builtin_amdgcn_mfma_f32_16x16x32_bf16(af[mi], bfr[ni], acc[mi][ni], 0, 0, 0);
    }
    __syncthreads();
  }
  #pragma unroll
  for (int mi = 0; mi < 4; ++mi) {
    #pragma unroll
    for (int ni = 0; ni < 4; ++ni) {
      int r0 = m0 + wm + mi * 16 + ((lane >> 4) * 4);
      int c  = n0 + wn + ni * 16 + (lane & 15);
      #pragma unroll
      for (int j = 0; j < 4; ++j)
        gx[(size_t)(r0 + j) * GXC + c] = gxstore<GXT>(acc[mi][ni][j]);
    }
  }
}

// ---------------- recurrence: 4 CUs/chain, fence-free tagged exchange -------
// FINAL (revert to R11, the measured best: rnn 2.30 ms rocprof, absmax
// 5.9e-3). Evidence this is a local optimum pinned by cross-CU handoff
// latency: R10 (deeper polls, +34%), R13 (MFMA core, +28%), R14 (packed
// publish + s_sleep throttle, +15%) all regressed; compute, occupancy and
// bandwidth are each far from their limits (VALUBusy 46%, HBM 2%, 0 bank
// conflicts). Step = dots -> butterfly -> epilogue+publish (relaxed agent
// store, tagged {it+1|h_f16}) -> 192 independent single-u64 polls -> barrier,
// 1024 strictly serial steps.

#define H16(M) M(0) M(1) M(2) M(3) M(4) M(5) M(6) M(7) \
               M(8) M(9) M(10) M(11) M(12) M(13) M(14) M(15)

#define WDECL(i) uint4 W0_##i, W1_##i, W2_##i;
#define WLOAD(i) W0_##i = wq[(i) * 512]; \
                 W1_##i = wq[(16 + (i)) * 512]; \
                 W2_##i = wq[(32 + (i)) * 512];
#define WPIN(i) asm volatile("" : "+v"(W0_##i.x), "+v"(W0_##i.y), "+v"(W0_##i.z), "+v"(W0_##i.w), \
                                  "+v"(W1_##i.x), "+v"(W1_##i.y), "+v"(W1_##i.z), "+v"(W1_##i.w), \
                                  "+v"(W2_##i.x), "+v"(W2_##i.y), "+v"(W2_##i.z), "+v"(W2_##i.w));
#define CHUNK(i) { uint4 Hq = hq4[i]; \
  s0 = dot2f(W0_##i.x, Hq.x, s0); s0 = dot2f(W0_##i.y, Hq.y, s0); \
  s0 = dot2f(W0_##i.z, Hq.z, s0); s0 = dot2f(W0_##i.w, Hq.w, s0); \
  s1 = dot2f(W1_##i.x, Hq.x, s1); s1 = dot2f(W1_##i.y, Hq.y, s1); \
  s1 = dot2f(W1_##i.z, Hq.z, s1); s1 = dot2f(W1_##i.w, Hq.w, s1); \
  s2 = dot2f(W2_##i.x, Hq.x, s2); s2 = dot2f(W2_##i.y, Hq.y, s2); \
  s2 = dot2f(W2_##i.z, Hq.z, s2); s2 = dot2f(W2_##i.w, Hq.w, s2); }

#define TAGOK1(a, want) \
  (((((unsigned)((a) >> 16)) & 0xffffu) == (want)) & \
   ((((unsigned)((a) >> 48))) == (want)))

template<typename GXT>
__global__ __launch_bounds__(512, 2)
void rnn_kernel(const GXT* __restrict__ gx, const unsigned* __restrict__ whh2,
                const float* __restrict__ bih_f, const float* __restrict__ bhh_f,
                const float* __restrict__ bih_b, const float* __restrict__ bhh_b,
                const int* __restrict__ layout, float* __restrict__ out,
                unsigned* __restrict__ hx) {
  __shared__ unsigned hbufw[544];            // 2 parities x (4 quarters x 68 words)
  __shared__ int lay[Ww + 1];
  const int tid   = threadIdx.x;
  const int j     = blockIdx.x >> 6;         // shard: siblings {c, c+64, c+128, c+192}
  const int chain = blockIdx.x & 63;
  const int dir   = chain >> 5;
  const int b     = chain & 31;
  const int c     = tid >> 2;                // local hcol 0..127
  const int q     = tid & 3;                 // K-quarter
  const int col   = j * 128 + c;             // global hcol

  const uint4* wq = reinterpret_cast<const uint4*>(whh2)
                    + (size_t)(dir * 4 + j) * 48 * 512 + tid;
  H16(WDECL)
  H16(WLOAD)
  H16(WPIN)

  float bi0 = 0.f, bi1 = 0.f, bi2 = 0.f, bh0 = 0.f, bh1 = 0.f, bh2 = 0.f;
  if (q == 0) {
    const float* bi = dir ? bih_b : bih_f;
    const float* bh = dir ? bhh_b : bhh_f;
    bi0 = bi[col]; bi1 = bi[512 + col]; bi2 = bi[1024 + col];
    bh0 = bh[col]; bh1 = bh[512 + col]; bh2 = bh[1024 + col];
  }
  if (tid <= Ww) lay[tid] = layout[b * (Ww + 1) + tid];
  hbufw[tid] = 0u;
  if (tid < 32) hbufw[512 + tid] = 0u;       // h0 = 0, both parities
  __syncthreads();

  float h = 0.f, mx = -3.0e38f;
  int t = dir ? (Ss - 1) : 0;
  const int tstep = dir ? -1 : 1;
  int seg = dir ? (Ww - 1) : 0;
  int p = 0;

  // gx prefetch: current step's values live in (gr,gz,gn)
  float gr = 0.f, gz = 0.f, gn = 0.f;
  if (q == 0) {
    const GXT* gp = gx + (size_t)(t * Bb + b) * GXC + dir * 1536 + col;
    gr = gxload<GXT>(gp[0]); gz = gxload<GXT>(gp[512]); gn = gxload<GXT>(gp[1024]);
  }

  #pragma unroll 1
  for (int it = 0; it < Ss; ++it, t += tstep) {
    float ngr = 0.f, ngz = 0.f, ngn = 0.f;
    if (q == 0 && it + 1 < Ss) {             // issue NEXT step's gx now (~2us cover)
      const GXT* gp = gx + (size_t)((t + tstep) * Bb + b) * GXC + dir * 1536 + col;
      ngr = gxload<GXT>(gp[0]); ngz = gxload<GXT>(gp[512]); ngn = gxload<GXT>(gp[1024]);
    }
    float s0 = 0.f, s1 = 0.f, s2 = 0.f;
    const uint4* hq4 = reinterpret_cast<const uint4*>(hbufw) + p * 68 + q * 17;
    H16(CHUNK)
    H16(WPIN)                                // keep weights loop-carried in regs
    { float u;                               // quad butterfly over K-quarters
      u = __shfl_xor(s0, 1); s0 += u; u = __shfl_xor(s0, 2); s0 += u;
      u = __shfl_xor(s1, 1); s1 += u; u = __shfl_xor(s1, 2); s1 += u;
      u = __shfl_xor(s2, 1); s2 += u; u = __shfl_xor(s2, 2); s2 += u; }
    const int P = p ^ 1;
    if (q == 0) {
      float rs = gr + bi0 + bh0 + s0;
      float zs = gz + bi1 + bh1 + s1;
      float nh = bh2 + s2;                   // gh_n incl. b_hh_n (scaled by r)
      float r = 1.f / (1.f + __expf(-rs));
      float z = 1.f / (1.f + __expf(-zs));
      float x = gn + bi2 + r * nh;
      x = fminf(fmaxf(x, -15.f), 15.f);
      float e = __expf(2.f * x);
      float n = (e - 1.f) / (e + 1.f);       // tanh
      h = (1.f - z) * n + z * h;
      unsigned hb16 = (unsigned)__builtin_bit_cast(unsigned short, (_Float16)h);
      __hip_atomic_store(hx + ((((size_t)P * 64 + chain) * 4 + j) << 7) + c,
                         (((unsigned)(it + 1)) << 16) | hb16,
                         __ATOMIC_RELAXED, __HIP_MEMORY_SCOPE_AGENT);
      mx = fmaxf(mx, h);
      reinterpret_cast<_Float16*>(hbufw)[((P * 272 + j * 68 + (c >> 1)) << 1) | (c & 1)]
          = (_Float16)h;                     // own shard of h_{it+1} (local)
      bool flush = dir ? (t == lay[seg]) : (t + 1 == lay[seg + 1]);
      if (flush) {
        out[(size_t)(b * Ww + seg) * 1024 + dir * 512 + col] = mx;
        mx = -3.0e38f;
        seg += tstep;
      }
    }
    // gather: touches only parity-P sibling slots (disjoint from this step's
    // parity-p reads and own-slot writes); barrier C orders for next step.
    if (it + 1 < Ss && tid < 192) {          // 192 threads x ONE u64 each
      int s = tid >> 6, qd = tid & 63;       // u64 qd covers columns 2qd, 2qd+1
      int sib = s + (s >= j);
      const u64* src = reinterpret_cast<const u64*>(
          hx + ((((size_t)P * 64 + chain) * 4 + sib) << 7) + (qd << 1));
      const unsigned want = (unsigned)(it + 1);
      u64 a;
      for (;;) {
        a = __hip_atomic_load(src, __ATOMIC_RELAXED, __HIP_MEMORY_SCOPE_AGENT);
        if (TAGOK1(a, want)) break;
      }
      hbufw[P * 272 + sib * 68 + qd] =
          ((unsigned)a & 0xffffu) | (((unsigned)(a >> 32) & 0xffffu) << 16);
    }
    __syncthreads();                         // C: full h_{it+1} in LDS
    p = P;
    gr = ngr; gz = ngz; gn = ngn;
  }
  if (q == 0)                                // final hidden [2][B][H]
    out[(size_t)Bb * Ww * 1024 + (size_t)dir * (Bb * Hh) + b * Hh + col] = h;
}

// ---------------- host launcher ----------------
extern "C" void kernel_launch(void* const* d_in, const int* in_sizes, int n_in,
                              void* d_out, int out_size, void* d_ws, size_t ws_size,
                              hipStream_t stream) {
  const int*   seq    = (const int*)  d_in[0];
  const int*   layout = (const int*)  d_in[3];
  const float* emb    = (const float*)d_in[4];
  const float* Wih_f  = (const float*)d_in[5];
  const float* Whh_f  = (const float*)d_in[6];
  const float* bih_f  = (const float*)d_in[7];
  const float* bhh_f  = (const float*)d_in[8];
  const float* Wih_b  = (const float*)d_in[9];
  const float* Whh_b  = (const float*)d_in[10];
  const float* bih_b  = (const float*)d_in[11];
  const float* bhh_b  = (const float*)d_in[12];
  float* out = (float*)d_out;

  char* ws = (char*)d_ws;
  unsigned short* embb  = (unsigned short*)ws;                      // 32,768,000 B
  unsigned short* wihb  = (unsigned short*)(ws + 32768000);         //  3,145,728 B
  unsigned*       whh2  = (unsigned*)      (ws + 35913728);         //  3,145,728 B
  unsigned*       hxw   = (unsigned*)      (ws + 39059456);         //    262,144 B
  void*           gxp   = (void*)          (ws + 39321600);

  const size_t need_f32 = 39321600ULL + (size_t)MR * GXC * 4;       // ~442.0 MB
  const size_t need_b16 = 39321600ULL + (size_t)MR * GXC * 2;       // ~240.6 MB
  if (ws_size < need_b16) return;

  prep_emb<<<(Vv * Ee) / 4 / 256, 256, 0, stream>>>(emb, embb);
  prep_wih<<<(GXC * Ee) / 4 / 256, 256, 0, stream>>>(Wih_f, Wih_b, wihb);
  prep_whh<<<(2 * 4 * 48 * 512 * 4) / 256, 256, 0, stream>>>(Whh_f, Whh_b, whh2);
  zero_hx<<<256, 256, 0, stream>>>(hxw);      // stream-ordered: runs before rnn

  if (ws_size >= need_f32) {
    gx_gemm<float><<<dim3(GXC / 128, MR / 128), 256, 0, stream>>>(seq, embb, wihb, (float*)gxp);
    rnn_kernel<float><<<256, 512, 0, stream>>>((const float*)gxp, whh2,
                                               bih_f, bhh_f, bih_b, bhh_b, layout, out, hxw);
  } else {
    gx_gemm<__hip_bfloat16><<<dim3(GXC / 128, MR / 128), 256, 0, stream>>>(seq, embb, wihb, (__hip_bfloat16*)gxp);
    rnn_kernel<__hip_bfloat16><<<256, 512, 0, stream>>>((const __hip_bfloat16*)gxp, whh2,
                                                        bih_f, bhh_f, bih_b, bhh_b, layout, out, hxw);
  }
}